// Round 5
// baseline (306.364 us; speedup 1.0000x reference)
//
#include <hip/hip_runtime.h>

#define NN 1024
#define DD 256
#define HH 256

typedef __attribute__((ext_vector_type(8))) short short8;
typedef __attribute__((ext_vector_type(4))) float floatx4;

// ---- ws layout (bytes) ----
// Permuted h' space: 288 slots = [positives (P) | zero-pad to P32 | negatives | zero-pad]
#define ZB_OFF   0u           // bf16 zb[1024][256]                      512 KiB
#define WC_OFF   524288u      // bf16 Wcat[592][256]: rows 0..287 R-half (|w2|-scaled, perm),
                              //   288..575 C-half (-|w2|-scaled, perm), 576 wc, 577..591 zero
#define B1F_OFF  827392u      // f32 b1f[592]
#define PV_OFF   829760u      // int P (count of w2>0)
#define RF_OFF   1048576u     // f32 Rf[1024][288]   (perm+pad)          1.125 MiB
#define CT_OFF   2228224u     // float4 Ct4[72][1024]: Ct4[g][j] = 4 h' (4g..4g+3) of column j
#define KV_OFF   3407872u     // f32 Kv[1024]  (= z@wc + b2)

__device__ __forceinline__ unsigned short f2bf(float x) {  // RNE f32->bf16
  unsigned u = __float_as_uint(x);
  return (unsigned short)((u + 0x7FFFu + ((u >> 16) & 1u)) >> 16);
}

// ---------------- k0: prep ----------------
__global__ __launch_bounds__(256) void k0_prep(const float* __restrict__ z,
    const float* __restrict__ W1, const float* __restrict__ b1,
    const float* __restrict__ W2, const float* __restrict__ b2,
    char* __restrict__ ws) {
  const int b = blockIdx.x, t = threadIdx.x;
  unsigned short* zb = (unsigned short*)(ws + ZB_OFF);
  unsigned short* Wc = (unsigned short*)(ws + WC_OFF);
  float* b1f = (float*)(ws + B1F_OFF);

  if (b < 256) {                       // z -> bf16, 1 float4 per thread
    const int g = b * 256 + t;
    float4 v = ((const float4*)z)[g];
    ushort4 u;
    u.x = f2bf(v.x); u.y = f2bf(v.y); u.z = f2bf(v.z); u.w = f2bf(v.w);
    ((ushort4*)zb)[g] = u;
    return;
  }
  if (b < 400) {                       // Wcat rows q = 4*(b-256)+(t>>6) in [0,576)
    __shared__ unsigned long long masks[4];
    __shared__ short inv[288];
    const bool pos = W2[t] > 0.f;
    unsigned long long m = __ballot(pos);
    if ((t & 63) == 0) masks[t >> 6] = m;
    inv[t] = -1;
    if (t < 32) inv[256 + t] = -1;
    __syncthreads();
    int P = 0;
    #pragma unroll
    for (int w = 0; w < 4; ++w) P += __popcll(masks[w]);
    const int w = t >> 6;
    int below = __popcll(masks[w] & ((1ull << (t & 63)) - 1ull));
    #pragma unroll
    for (int wi = 0; wi < 4; ++wi) if (wi < w) below += __popcll(masks[wi]);
    const int P32 = (P + 31) & ~31;
    const int dest = pos ? below : (P32 + (t - below));
    inv[dest] = (short)t;
    __syncthreads();

    const int q = (b - 256) * 4 + (t >> 6);     // 0..575
    const int d0 = (t & 63) * 4;
    const bool topR = q < 288;
    const int hidx = topR ? q : q - 288;
    const short oh = inv[hidx];
    ushort4 u = {0, 0, 0, 0};
    float bias = 0.f;
    if (oh >= 0) {
      const float wa = fabsf(W2[oh]);
      const float sc = topR ? wa : -wa;          // C-half carries the negation (Cn = -C~)
      const float4 v = *(const float4*)(W1 + oh * 512 + (topR ? 0 : 256) + d0);
      u.x = f2bf(v.x * sc); u.y = f2bf(v.y * sc);
      u.z = f2bf(v.z * sc); u.w = f2bf(v.w * sc);
      bias = topR ? b1[oh] * wa : 0.f;
    }
    ((ushort4*)(Wc + q * 256))[d0 >> 2] = u;
    if (d0 == 0) b1f[q] = bias;
    if (b == 256 && t == 0) *(int*)(ws + PV_OFF) = P;
    return;
  }
  // b in [400,404): wc quarter: wc[d] = sum_h W2[h]*W1[h][256+d] -> Wcat row 576
  {
    __shared__ float part[4][64];
    const int w = t >> 6, dl = t & 63;
    const int d = (b - 400) * 64 + dl;
    float acc = 0.f;
    const float* col = W1 + 256 + d;
    #pragma unroll 8
    for (int h = w * 64; h < w * 64 + 64; ++h) acc += W2[h] * col[h * 512];
    part[w][dl] = acc;
    __syncthreads();
    if (w == 0) {
      float s = part[0][dl] + part[1][dl] + part[2][dl] + part[3][dl];
      Wc[576 * 256 + d] = f2bf(s);
    }
    if (b == 400) {
      for (int r = 577; r < 592; ++r) Wc[r * 256 + t] = 0;   // zero pad rows
      if (t == 0) b1f[576] = b2[0];
      if (t < 15) b1f[577 + t] = 0.f;
    }
  }
}

// ---------------- k1: fc1 GEMM via bf16 MFMA -> f32 outputs ----------------
__global__ __launch_bounds__(64) void k1_mfma(char* __restrict__ ws) {
  __shared__ float tile[16][17];
  const unsigned short* zb = (const unsigned short*)(ws + ZB_OFF);
  const unsigned short* Wcu = (const unsigned short*)(ws + WC_OFF);
  const float* b1f = (const float*)(ws + B1F_OFF);
  float* Rf = (float*)(ws + RF_OFF);
  float4* Ct4 = (float4*)(ws + CT_OFF);
  float* Kv = (float*)(ws + KV_OFF);

  const int l = threadIdx.x;
  const int i0 = blockIdx.x * 16, q0 = blockIdx.y * 16;
  const short* A = (const short*)zb + (i0 + (l & 15)) * 256 + ((l >> 4) * 8);
  const short* B = (const short*)Wcu + (q0 + (l & 15)) * 256 + ((l >> 4) * 8);
  floatx4 acc = {0.f, 0.f, 0.f, 0.f};
  #pragma unroll
  for (int kk = 0; kk < 8; ++kk) {
    short8 a  = *(const short8*)(A + kk * 32);
    short8 bb = *(const short8*)(B + kk * 32);
    acc = __builtin_amdgcn_mfma_f32_16x16x32_bf16(a, bb, acc, 0, 0, 0);
  }
  const int col = l & 15, r0 = (l >> 4) * 4;   // D: col=lane&15, row=(lane>>4)*4+reg
  if (q0 < 288) {
    const float bias = b1f[q0 + col];
    #pragma unroll
    for (int q = 0; q < 4; ++q)
      Rf[(i0 + r0 + q) * 288 + q0 + col] = acc[q] + bias;
  } else if (q0 < 576) {
    #pragma unroll
    for (int q = 0; q < 4; ++q) tile[r0 + q][col] = acc[q];   // tile[j_local][h_local]
    __syncthreads();
    const int jl = l & 15, qg = l >> 4;         // qg: which 4-h group
    float4 v;
    v.x = tile[jl][qg * 4 + 0]; v.y = tile[jl][qg * 4 + 1];
    v.z = tile[jl][qg * 4 + 2]; v.w = tile[jl][qg * 4 + 3];
    const int q0c = q0 - 288;
    Ct4[((q0c >> 2) + qg) * 1024 + (i0 + jl)] = v;
  } else if (col == 0) {
    const float bias = b1f[576];                // = b2
    #pragma unroll
    for (int q = 0; q < 4; ++q) Kv[i0 + r0 + q] = acc[q] + bias;
  }
}

// ---------------- k2: pairwise decode, 4-wave h-split + LDS combine ----------------
// Block = 256 threads (4 waves), tile 8i x 64j. Wave w computes chunks {w, w+4, w+8<=8}
// (sign-pure 32-h chunks), partial-sums combined in LDS, then sigmoid+store.
// Grid 2048 blocks -> 2048 threads/CU (cap), 8 waves/SIMD.
__global__ __launch_bounds__(256, 8) void k2_pair(const float* __restrict__ Rf,
    const float4* __restrict__ Ct4, const float* __restrict__ Kv,
    const int* __restrict__ Pp, float* __restrict__ out) {
  __shared__ float part[4][8][64];
  const int t = threadIdx.x;
  const int lane = t & 63, w = t >> 6;          // wave id 0..3 (wave-uniform)
  const int i0 = blockIdx.x * 8, j0 = blockIdx.y * 64;
  const int j = j0 + lane;
  const int P = Pp[0];

  float acc[8] = {};

  #pragma unroll 1
  for (int s = 0; s < 3; ++s) {
    const int ch = w + s * 4;                   // wave-uniform chunk id
    if (ch > 8) break;                          // only wave 0 runs s=2 (chunk 8)
    // batch-load this chunk's C window: 8 coalesced dwordx4 (32 VGPR, static idx)
    float4 cw[8];
    #pragma unroll
    for (int g = 0; g < 8; ++g) cw[g] = Ct4[(ch * 8 + g) * 1024 + j];
    const float sch = (ch * 32 < P) ? 1.f : -1.f;
    #pragma unroll
    for (int i = 0; i < 8; ++i) {
      const float* rrow = Rf + (i0 + i) * 288 + ch * 32;  // lane-uniform -> s_load
      float p0 = 0.f, p1 = 0.f;
      #pragma unroll
      for (int g = 0; g < 8; ++g) {
        const float4 c = cw[g];
        p0 += fmaxf(rrow[4 * g + 0], c.x);
        p1 += fmaxf(rrow[4 * g + 1], c.y);
        p0 += fmaxf(rrow[4 * g + 2], c.z);
        p1 += fmaxf(rrow[4 * g + 3], c.w);
      }
      acc[i] = fmaf(sch, p0 + p1, acc[i]);
    }
  }

  #pragma unroll
  for (int i = 0; i < 8; ++i) part[w][i][lane] = acc[i];
  __syncthreads();

  // combine: 256 threads x 2 outputs
  const int jj = t & 63, ih = (t >> 6) * 2;
  const float kv = Kv[j0 + jj];
  #pragma unroll
  for (int u = 0; u < 2; ++u) {
    const int i = ih + u;
    const float x = part[0][i][jj] + part[1][i][jj] + part[2][i][jj] + part[3][i][jj] + kv;
    out[(i0 + i) * NN + j0 + jj] = 1.f / (1.f + __expf(-x));
  }
}

extern "C" void kernel_launch(void* const* d_in, const int* in_sizes, int n_in,
                              void* d_out, int out_size, void* d_ws, size_t ws_size,
                              hipStream_t stream) {
  const float* z  = (const float*)d_in[0];
  const float* W1 = (const float*)d_in[1];
  const float* b1 = (const float*)d_in[2];
  const float* W2 = (const float*)d_in[3];
  const float* b2 = (const float*)d_in[4];
  float* out = (float*)d_out;
  char* ws = (char*)d_ws;

  k0_prep<<<404, 256, 0, stream>>>(z, W1, b1, W2, b2, ws);
  k1_mfma<<<dim3(64, 37), 64, 0, stream>>>(ws);
  k2_pair<<<dim3(128, 16), 256, 0, stream>>>(
      (const float*)(ws + RF_OFF), (const float4*)(ws + CT_OFF),
      (const float*)(ws + KV_OFF), (const int*)(ws + PV_OFF), out);
}

// Round 6
// 87.953 us; speedup vs baseline: 3.4833x; 3.4833x over previous
//
#include <hip/hip_runtime.h>

#define NN 1024
#define DD 256
#define HH 256

typedef __attribute__((ext_vector_type(8))) short short8;
typedef __attribute__((ext_vector_type(4))) float floatx4;

// ---- ws layout (bytes) ----
// Permuted h' space: 288 slots = [positives (P) | zero-pad to P32 | negatives | zero-pad]
#define ZB_OFF   0u           // bf16 zb[1024][256]                      512 KiB
#define WC_OFF   524288u      // bf16 Wcat[592][256]: rows 0..287 R-half (|w2|-scaled, perm),
                              //   288..575 C-half (-|w2|-scaled, perm), 576 wc, 577..591 zero
#define B1F_OFF  827392u      // f32 b1f[592]
#define PV_OFF   829760u      // int P (count of w2>0)
#define RF_OFF   1048576u     // f32 Rf[1024][288]   (perm+pad)          1.125 MiB
#define CT_OFF   2228224u     // float4 Ct4[72][1024]: Ct4[g][j] = 4 h' (4g..4g+3) of column j
#define KV_OFF   3407872u     // f32 Kv[1024]  (= z@wc + b2)

__device__ __forceinline__ unsigned short f2bf(float x) {  // RNE f32->bf16
  unsigned u = __float_as_uint(x);
  return (unsigned short)((u + 0x7FFFu + ((u >> 16) & 1u)) >> 16);
}

// ---------------- k0: prep ----------------
__global__ __launch_bounds__(256) void k0_prep(const float* __restrict__ z,
    const float* __restrict__ W1, const float* __restrict__ b1,
    const float* __restrict__ W2, const float* __restrict__ b2,
    char* __restrict__ ws) {
  const int b = blockIdx.x, t = threadIdx.x;
  unsigned short* zb = (unsigned short*)(ws + ZB_OFF);
  unsigned short* Wc = (unsigned short*)(ws + WC_OFF);
  float* b1f = (float*)(ws + B1F_OFF);

  if (b < 256) {                       // z -> bf16, 1 float4 per thread
    const int g = b * 256 + t;
    float4 v = ((const float4*)z)[g];
    ushort4 u;
    u.x = f2bf(v.x); u.y = f2bf(v.y); u.z = f2bf(v.z); u.w = f2bf(v.w);
    ((ushort4*)zb)[g] = u;
    return;
  }
  if (b < 400) {                       // Wcat rows q = 4*(b-256)+(t>>6) in [0,576)
    __shared__ unsigned long long masks[4];
    __shared__ short inv[288];
    const bool pos = W2[t] > 0.f;
    unsigned long long m = __ballot(pos);
    if ((t & 63) == 0) masks[t >> 6] = m;
    inv[t] = -1;
    if (t < 32) inv[256 + t] = -1;
    __syncthreads();
    int P = 0;
    #pragma unroll
    for (int w = 0; w < 4; ++w) P += __popcll(masks[w]);
    const int w = t >> 6;
    int below = __popcll(masks[w] & ((1ull << (t & 63)) - 1ull));
    #pragma unroll
    for (int wi = 0; wi < 4; ++wi) if (wi < w) below += __popcll(masks[wi]);
    const int P32 = (P + 31) & ~31;
    const int dest = pos ? below : (P32 + (t - below));
    inv[dest] = (short)t;
    __syncthreads();

    const int q = (b - 256) * 4 + (t >> 6);     // 0..575
    const int d0 = (t & 63) * 4;
    const bool topR = q < 288;
    const int hidx = topR ? q : q - 288;
    const short oh = inv[hidx];
    ushort4 u = {0, 0, 0, 0};
    float bias = 0.f;
    if (oh >= 0) {
      const float wa = fabsf(W2[oh]);
      const float sc = topR ? wa : -wa;          // C-half carries the negation (Cn = -C~)
      const float4 v = *(const float4*)(W1 + oh * 512 + (topR ? 0 : 256) + d0);
      u.x = f2bf(v.x * sc); u.y = f2bf(v.y * sc);
      u.z = f2bf(v.z * sc); u.w = f2bf(v.w * sc);
      bias = topR ? b1[oh] * wa : 0.f;
    }
    ((ushort4*)(Wc + q * 256))[d0 >> 2] = u;
    if (d0 == 0) b1f[q] = bias;
    if (b == 256 && t == 0) *(int*)(ws + PV_OFF) = P;
    return;
  }
  // b in [400,404): wc quarter: wc[d] = sum_h W2[h]*W1[h][256+d] -> Wcat row 576
  {
    __shared__ float part[4][64];
    const int w = t >> 6, dl = t & 63;
    const int d = (b - 400) * 64 + dl;
    float acc = 0.f;
    const float* col = W1 + 256 + d;
    #pragma unroll 8
    for (int h = w * 64; h < w * 64 + 64; ++h) acc += W2[h] * col[h * 512];
    part[w][dl] = acc;
    __syncthreads();
    if (w == 0) {
      float s = part[0][dl] + part[1][dl] + part[2][dl] + part[3][dl];
      Wc[576 * 256 + d] = f2bf(s);
    }
    if (b == 400) {
      for (int r = 577; r < 592; ++r) Wc[r * 256 + t] = 0;   // zero pad rows
      if (t == 0) b1f[576] = b2[0];
      if (t < 15) b1f[577 + t] = 0.f;
    }
  }
}

// ---------------- k1: fc1 GEMM via bf16 MFMA -> f32 outputs ----------------
__global__ __launch_bounds__(64) void k1_mfma(char* __restrict__ ws) {
  __shared__ float tile[16][17];
  const unsigned short* zb = (const unsigned short*)(ws + ZB_OFF);
  const unsigned short* Wcu = (const unsigned short*)(ws + WC_OFF);
  const float* b1f = (const float*)(ws + B1F_OFF);
  float* Rf = (float*)(ws + RF_OFF);
  float4* Ct4 = (float4*)(ws + CT_OFF);
  float* Kv = (float*)(ws + KV_OFF);

  const int l = threadIdx.x;
  const int i0 = blockIdx.x * 16, q0 = blockIdx.y * 16;
  const short* A = (const short*)zb + (i0 + (l & 15)) * 256 + ((l >> 4) * 8);
  const short* B = (const short*)Wcu + (q0 + (l & 15)) * 256 + ((l >> 4) * 8);
  floatx4 acc = {0.f, 0.f, 0.f, 0.f};
  #pragma unroll
  for (int kk = 0; kk < 8; ++kk) {
    short8 a  = *(const short8*)(A + kk * 32);
    short8 bb = *(const short8*)(B + kk * 32);
    acc = __builtin_amdgcn_mfma_f32_16x16x32_bf16(a, bb, acc, 0, 0, 0);
  }
  const int col = l & 15, r0 = (l >> 4) * 4;   // D: col=lane&15, row=(lane>>4)*4+reg
  if (q0 < 288) {
    const float bias = b1f[q0 + col];
    #pragma unroll
    for (int q = 0; q < 4; ++q)
      Rf[(i0 + r0 + q) * 288 + q0 + col] = acc[q] + bias;
  } else if (q0 < 576) {
    #pragma unroll
    for (int q = 0; q < 4; ++q) tile[r0 + q][col] = acc[q];   // tile[j_local][h_local]
    __syncthreads();
    const int jl = l & 15, qg = l >> 4;         // qg: which 4-h group
    float4 v;
    v.x = tile[jl][qg * 4 + 0]; v.y = tile[jl][qg * 4 + 1];
    v.z = tile[jl][qg * 4 + 2]; v.w = tile[jl][qg * 4 + 3];
    const int q0c = q0 - 288;
    Ct4[((q0c >> 2) + qg) * 1024 + (i0 + jl)] = v;
  } else if (col == 0) {
    const float bias = b1f[576];                // = b2
    #pragma unroll
    for (int q = 0; q < 4; ++q) Kv[i0 + r0 + q] = acc[q] + bias;
  }
}

// ---------------- k2: pairwise decode, 4-wave h-split, NO forced occupancy ----------------
// Block = 256 threads (4 waves), tile 16i x 64j. Wave w computes sign-pure 32-h chunks
// {w, w+4, w+8<=8}; partials combined in LDS; sigmoid+store by all threads.
// launch_bounds(256,4): 128-VGPR cap -> cw[8](32)+acc[16](16)+addr fits, zero spill,
// 4 waves/SIMD resident (r5's (256,8) forced 32 VGPR -> 750MB scratch -> 294us).
__global__ __launch_bounds__(256, 4) void k2_pair(const float* __restrict__ Rf,
    const float4* __restrict__ Ct4, const float* __restrict__ Kv,
    const int* __restrict__ Pp, float* __restrict__ out) {
  __shared__ float part[4][16][64];
  const int t = threadIdx.x;
  const int lane = t & 63, w = t >> 6;          // wave id 0..3 (wave-uniform)
  const int i0 = blockIdx.x * 16, j0 = blockIdx.y * 64;
  const int j = j0 + lane;
  const int P = Pp[0];

  float acc[16] = {};

  #pragma unroll 1
  for (int s = 0; s < 3; ++s) {
    const int ch = w + s * 4;                   // wave-uniform chunk id
    if (ch > 8) break;                          // only wave 0 runs s=2 (chunk 8)
    // batch-load this chunk's C window: 8 coalesced dwordx4 (32 VGPR, static idx)
    float4 cw[8];
    #pragma unroll
    for (int g = 0; g < 8; ++g) cw[g] = Ct4[(ch * 8 + g) * 1024 + j];
    const float sch = (ch * 32 < P) ? 1.f : -1.f;
    #pragma unroll
    for (int i = 0; i < 16; ++i) {
      const float* rrow = Rf + (i0 + i) * 288 + ch * 32;  // lane-uniform -> s_load
      float p0 = 0.f, p1 = 0.f;
      #pragma unroll
      for (int g = 0; g < 8; ++g) {
        const float4 c = cw[g];
        p0 += fmaxf(rrow[4 * g + 0], c.x);
        p1 += fmaxf(rrow[4 * g + 1], c.y);
        p0 += fmaxf(rrow[4 * g + 2], c.z);
        p1 += fmaxf(rrow[4 * g + 3], c.w);
      }
      acc[i] = fmaf(sch, p0 + p1, acc[i]);
    }
  }

  #pragma unroll
  for (int i = 0; i < 16; ++i) part[w][i][lane] = acc[i];
  __syncthreads();

  // combine: 256 threads x 4 outputs
  const int jj = t & 63, ib = (t >> 6) * 4;
  const float kv = Kv[j0 + jj];
  #pragma unroll
  for (int u = 0; u < 4; ++u) {
    const int i = ib + u;
    const float x = part[0][i][jj] + part[1][i][jj] + part[2][i][jj] + part[3][i][jj] + kv;
    out[(i0 + i) * NN + j0 + jj] = 1.f / (1.f + __expf(-x));
  }
}

extern "C" void kernel_launch(void* const* d_in, const int* in_sizes, int n_in,
                              void* d_out, int out_size, void* d_ws, size_t ws_size,
                              hipStream_t stream) {
  const float* z  = (const float*)d_in[0];
  const float* W1 = (const float*)d_in[1];
  const float* b1 = (const float*)d_in[2];
  const float* W2 = (const float*)d_in[3];
  const float* b2 = (const float*)d_in[4];
  float* out = (float*)d_out;
  char* ws = (char*)d_ws;

  k0_prep<<<404, 256, 0, stream>>>(z, W1, b1, W2, b2, ws);
  k1_mfma<<<dim3(64, 37), 64, 0, stream>>>(ws);
  k2_pair<<<dim3(64, 16), 256, 0, stream>>>(
      (const float*)(ws + RF_OFF), (const float4*)(ws + CT_OFF),
      (const float*)(ws + KV_OFF), (const int*)(ws + PV_OFF), out);
}

// Round 7
// 56.684 us; speedup vs baseline: 5.4048x; 1.5516x over previous
//
#include <hip/hip_runtime.h>

#define NN 1024
#define DD 256
#define HH 256

typedef __attribute__((ext_vector_type(8))) short short8;
typedef __attribute__((ext_vector_type(4))) float floatx4;

// ---- ws layout (bytes) ----
// Permuted h' space: 288 slots = [positives (P) | zero-pad to P32 | negatives | zero-pad]
#define ZB_OFF   0u           // bf16 zb[1024][256]                      512 KiB
#define WC_OFF   524288u      // bf16 Wcat[592][256]: rows 0..287 R-half (|w2|-scaled, perm),
                              //   288..575 C-half (-|w2|-scaled, perm), 576 wc, 577..591 zero
#define B1F_OFF  827392u      // f32 b1f[592]
#define PV_OFF   829760u      // int P (count of w2>0)
#define RF_OFF   1048576u     // f32 Rf[1024][288]   (perm+pad)          1.125 MiB
#define CT_OFF   2228224u     // float4 Ct4[72][1024]: Ct4[g][j] = 4 h' (4g..4g+3) of column j
#define KV_OFF   3407872u     // f32 Kv[1024]  (= z@wc + b2)

__device__ __forceinline__ unsigned short f2bf(float x) {  // RNE f32->bf16
  unsigned u = __float_as_uint(x);
  return (unsigned short)((u + 0x7FFFu + ((u >> 16) & 1u)) >> 16);
}

// ---------------- k0: prep ----------------
__global__ __launch_bounds__(256) void k0_prep(const float* __restrict__ z,
    const float* __restrict__ W1, const float* __restrict__ b1,
    const float* __restrict__ W2, const float* __restrict__ b2,
    char* __restrict__ ws) {
  const int b = blockIdx.x, t = threadIdx.x;
  unsigned short* zb = (unsigned short*)(ws + ZB_OFF);
  unsigned short* Wc = (unsigned short*)(ws + WC_OFF);
  float* b1f = (float*)(ws + B1F_OFF);

  if (b < 256) {                       // z -> bf16, 1 float4 per thread
    const int g = b * 256 + t;
    float4 v = ((const float4*)z)[g];
    ushort4 u;
    u.x = f2bf(v.x); u.y = f2bf(v.y); u.z = f2bf(v.z); u.w = f2bf(v.w);
    ((ushort4*)zb)[g] = u;
    return;
  }
  if (b < 400) {                       // Wcat rows q = 4*(b-256)+(t>>6) in [0,576)
    __shared__ unsigned long long masks[4];
    __shared__ short inv[288];
    const bool pos = W2[t] > 0.f;
    unsigned long long m = __ballot(pos);
    if ((t & 63) == 0) masks[t >> 6] = m;
    inv[t] = -1;
    if (t < 32) inv[256 + t] = -1;
    __syncthreads();
    int P = 0;
    #pragma unroll
    for (int w = 0; w < 4; ++w) P += __popcll(masks[w]);
    const int w = t >> 6;
    int below = __popcll(masks[w] & ((1ull << (t & 63)) - 1ull));
    #pragma unroll
    for (int wi = 0; wi < 4; ++wi) if (wi < w) below += __popcll(masks[wi]);
    const int P32 = (P + 31) & ~31;
    const int dest = pos ? below : (P32 + (t - below));
    inv[dest] = (short)t;
    __syncthreads();

    const int q = (b - 256) * 4 + (t >> 6);     // 0..575
    const int d0 = (t & 63) * 4;
    const bool topR = q < 288;
    const int hidx = topR ? q : q - 288;
    const short oh = inv[hidx];
    ushort4 u = {0, 0, 0, 0};
    float bias = 0.f;
    if (oh >= 0) {
      const float wa = fabsf(W2[oh]);
      const float sc = topR ? wa : -wa;          // C-half carries the negation (Cn = -C~)
      const float4 v = *(const float4*)(W1 + oh * 512 + (topR ? 0 : 256) + d0);
      u.x = f2bf(v.x * sc); u.y = f2bf(v.y * sc);
      u.z = f2bf(v.z * sc); u.w = f2bf(v.w * sc);
      bias = topR ? b1[oh] * wa : 0.f;
    }
    ((ushort4*)(Wc + q * 256))[d0 >> 2] = u;
    if (d0 == 0) b1f[q] = bias;
    if (b == 256 && t == 0) *(int*)(ws + PV_OFF) = P;
    return;
  }
  // b in [400,404): wc quarter: wc[d] = sum_h W2[h]*W1[h][256+d] -> Wcat row 576
  {
    __shared__ float part[4][64];
    const int w = t >> 6, dl = t & 63;
    const int d = (b - 400) * 64 + dl;
    float acc = 0.f;
    const float* col = W1 + 256 + d;
    #pragma unroll 8
    for (int h = w * 64; h < w * 64 + 64; ++h) acc += W2[h] * col[h * 512];
    part[w][dl] = acc;
    __syncthreads();
    if (w == 0) {
      float s = part[0][dl] + part[1][dl] + part[2][dl] + part[3][dl];
      Wc[576 * 256 + d] = f2bf(s);
    }
    if (b == 400) {
      for (int r = 577; r < 592; ++r) Wc[r * 256 + t] = 0;   // zero pad rows
      if (t == 0) b1f[576] = b2[0];
      if (t < 15) b1f[577 + t] = 0.f;
    }
  }
}

// ---------------- k1: fc1 GEMM via bf16 MFMA -> f32 outputs ----------------
__global__ __launch_bounds__(64) void k1_mfma(char* __restrict__ ws) {
  __shared__ float tile[16][17];
  const unsigned short* zb = (const unsigned short*)(ws + ZB_OFF);
  const unsigned short* Wcu = (const unsigned short*)(ws + WC_OFF);
  const float* b1f = (const float*)(ws + B1F_OFF);
  float* Rf = (float*)(ws + RF_OFF);
  float4* Ct4 = (float4*)(ws + CT_OFF);
  float* Kv = (float*)(ws + KV_OFF);

  const int l = threadIdx.x;
  const int i0 = blockIdx.x * 16, q0 = blockIdx.y * 16;
  const short* A = (const short*)zb + (i0 + (l & 15)) * 256 + ((l >> 4) * 8);
  const short* B = (const short*)Wcu + (q0 + (l & 15)) * 256 + ((l >> 4) * 8);
  floatx4 acc = {0.f, 0.f, 0.f, 0.f};
  #pragma unroll
  for (int kk = 0; kk < 8; ++kk) {
    short8 a  = *(const short8*)(A + kk * 32);
    short8 bb = *(const short8*)(B + kk * 32);
    acc = __builtin_amdgcn_mfma_f32_16x16x32_bf16(a, bb, acc, 0, 0, 0);
  }
  const int col = l & 15, r0 = (l >> 4) * 4;   // D: col=lane&15, row=(lane>>4)*4+reg
  if (q0 < 288) {
    const float bias = b1f[q0 + col];
    #pragma unroll
    for (int q = 0; q < 4; ++q)
      Rf[(i0 + r0 + q) * 288 + q0 + col] = acc[q] + bias;
  } else if (q0 < 576) {
    #pragma unroll
    for (int q = 0; q < 4; ++q) tile[r0 + q][col] = acc[q];   // tile[j_local][h_local]
    __syncthreads();
    const int jl = l & 15, qg = l >> 4;         // qg: which 4-h group
    float4 v;
    v.x = tile[jl][qg * 4 + 0]; v.y = tile[jl][qg * 4 + 1];
    v.z = tile[jl][qg * 4 + 2]; v.w = tile[jl][qg * 4 + 3];
    const int q0c = q0 - 288;
    Ct4[((q0c >> 2) + qg) * 1024 + (i0 + jl)] = v;
  } else if (col == 0) {
    const float bias = b1f[576];                // = b2
    #pragma unroll
    for (int q = 0; q < 4; ++q) Kv[i0 + r0 + q] = acc[q] + bias;
  }
}

// ---------------- k2: pairwise decode, 4-wave h-split, UNCONSTRAINED allocator ----------------
// Block = 256 threads (4 waves), tile 16i x 64j. Wave w computes sign-pure 32-h chunks
// {w, w+4, w+8<=8}; partials combined in LDS; sigmoid+store by all threads.
// NO min-waves launch_bounds arg: r5 (256,8)->32 VGPR and r6 (256,4)->64 VGPR both spilled
// (~110MB scratch writes). Live state needs ~80+ VGPR (cw[8]=32, acc[16]=16, addr/pipe).
// Free allocator -> ~96-128 VGPR, zero spill, natural 4-5 waves/SIMD.
__global__ __launch_bounds__(256) void k2_pair(const float* __restrict__ Rf,
    const float4* __restrict__ Ct4, const float* __restrict__ Kv,
    const int* __restrict__ Pp, float* __restrict__ out) {
  __shared__ float part[4][16][64];
  const int t = threadIdx.x;
  const int lane = t & 63, w = t >> 6;          // wave id 0..3 (wave-uniform)
  const int i0 = blockIdx.x * 16, j0 = blockIdx.y * 64;
  const int j = j0 + lane;
  const int P = Pp[0];

  float acc[16] = {};

  #pragma unroll 1
  for (int s = 0; s < 3; ++s) {
    const int ch = w + s * 4;                   // wave-uniform chunk id
    if (ch > 8) break;                          // only wave 0 runs s=2 (chunk 8)
    // batch-load this chunk's C window: 8 coalesced dwordx4 (32 VGPR, static idx)
    float4 cw[8];
    #pragma unroll
    for (int g = 0; g < 8; ++g) cw[g] = Ct4[(ch * 8 + g) * 1024 + j];
    const float sch = (ch * 32 < P) ? 1.f : -1.f;
    #pragma unroll
    for (int i = 0; i < 16; ++i) {
      const float* rrow = Rf + (i0 + i) * 288 + ch * 32;  // lane-uniform -> s_load
      float p0 = 0.f, p1 = 0.f;
      #pragma unroll
      for (int g = 0; g < 8; ++g) {
        const float4 c = cw[g];
        p0 += fmaxf(rrow[4 * g + 0], c.x);
        p1 += fmaxf(rrow[4 * g + 1], c.y);
        p0 += fmaxf(rrow[4 * g + 2], c.z);
        p1 += fmaxf(rrow[4 * g + 3], c.w);
      }
      acc[i] = fmaf(sch, p0 + p1, acc[i]);
    }
  }

  #pragma unroll
  for (int i = 0; i < 16; ++i) part[w][i][lane] = acc[i];
  __syncthreads();

  // combine: 256 threads x 4 outputs
  const int jj = t & 63, ib = (t >> 6) * 4;
  const float kv = Kv[j0 + jj];
  #pragma unroll
  for (int u = 0; u < 4; ++u) {
    const int i = ib + u;
    const float x = part[0][i][jj] + part[1][i][jj] + part[2][i][jj] + part[3][i][jj] + kv;
    out[(i0 + i) * NN + j0 + jj] = 1.f / (1.f + __expf(-x));
  }
}

extern "C" void kernel_launch(void* const* d_in, const int* in_sizes, int n_in,
                              void* d_out, int out_size, void* d_ws, size_t ws_size,
                              hipStream_t stream) {
  const float* z  = (const float*)d_in[0];
  const float* W1 = (const float*)d_in[1];
  const float* b1 = (const float*)d_in[2];
  const float* W2 = (const float*)d_in[3];
  const float* b2 = (const float*)d_in[4];
  float* out = (float*)d_out;
  char* ws = (char*)d_ws;

  k0_prep<<<404, 256, 0, stream>>>(z, W1, b1, W2, b2, ws);
  k1_mfma<<<dim3(64, 37), 64, 0, stream>>>(ws);
  k2_pair<<<dim3(64, 16), 256, 0, stream>>>(
      (const float*)(ws + RF_OFF), (const float4*)(ws + CT_OFF),
      (const float*)(ws + KV_OFF), (const int*)(ws + PV_OFF), out);
}

// Round 8
// 30.020 us; speedup vs baseline: 10.2053x; 1.8882x over previous
//
#include <hip/hip_runtime.h>

#define NN 1024
#define DD 256
#define HH 256

typedef __attribute__((ext_vector_type(8))) short short8;
typedef __attribute__((ext_vector_type(4))) float floatx4;
typedef __attribute__((ext_vector_type(4))) unsigned int uint4v;
typedef _Float16 half2v __attribute__((ext_vector_type(2)));

// ---- ws layout (bytes) ----
// Permuted h' space: 288 slots = [positives (P) | zero-pad to P32 | negatives | zero-pad]
// 144 h-pairs (hp), 36 hp-groups (hpg = hp/4), 9 sign-pure chunks of 32 h'.
#define ZB_OFF   0u           // bf16 zb[1024][256]                      512 KiB
#define WC_OFF   524288u      // bf16 Wcat[592][256] (R-half |w2|, C-half -|w2|, wc, pad)
#define B1F_OFF  827392u      // f32 b1f[592]
#define PV_OFF   829760u      // int P (count of w2>0)
#define R2_OFF   1048576u     // u32 R2[144][1024]: pk-f16 pair (2hp,2hp+1) of R~ for row i
#define CT_OFF   1703936u     // u32 Ct[36][1024][4]: pk-f16 C~ pairs, [hpg][j][hp&3]
#define KV_OFF   2293760u     // f32 Kv[1024]  (= z@wc + b2)

__device__ __forceinline__ unsigned short f2bf(float x) {  // RNE f32->bf16
  unsigned u = __float_as_uint(x);
  return (unsigned short)((u + 0x7FFFu + ((u >> 16) & 1u)) >> 16);
}

__device__ __forceinline__ unsigned int pkf16(float a, float b) {
  unsigned int lo = (unsigned int)__builtin_bit_cast(unsigned short, (_Float16)a);
  unsigned int hi = (unsigned int)__builtin_bit_cast(unsigned short, (_Float16)b);
  return lo | (hi << 16);
}

// core: acc += dot2( pk_max(r, c), mul )   -- 2 instr per 2 h per output
__device__ __forceinline__ void pkmaxdot(unsigned int r, unsigned int c,
                                         unsigned int mul, float& acc) {
  unsigned int m;
  asm("v_pk_max_f16 %0, %1, %2" : "=v"(m) : "v"(r), "v"(c));
#if __has_builtin(__builtin_amdgcn_fdot2)
  acc = __builtin_amdgcn_fdot2(__builtin_bit_cast(half2v, m),
                               __builtin_bit_cast(half2v, mul), acc, false);
#else
  asm("v_dot2_f32_f16 %0, %1, %2, %0" : "+v"(acc) : "v"(m), "v"(mul));
#endif
}

// ---------------- k0: prep (unchanged from r7) ----------------
__global__ __launch_bounds__(256) void k0_prep(const float* __restrict__ z,
    const float* __restrict__ W1, const float* __restrict__ b1,
    const float* __restrict__ W2, const float* __restrict__ b2,
    char* __restrict__ ws) {
  const int b = blockIdx.x, t = threadIdx.x;
  unsigned short* zb = (unsigned short*)(ws + ZB_OFF);
  unsigned short* Wc = (unsigned short*)(ws + WC_OFF);
  float* b1f = (float*)(ws + B1F_OFF);

  if (b < 256) {
    const int g = b * 256 + t;
    float4 v = ((const float4*)z)[g];
    ushort4 u;
    u.x = f2bf(v.x); u.y = f2bf(v.y); u.z = f2bf(v.z); u.w = f2bf(v.w);
    ((ushort4*)zb)[g] = u;
    return;
  }
  if (b < 400) {
    __shared__ unsigned long long masks[4];
    __shared__ short inv[288];
    const bool pos = W2[t] > 0.f;
    unsigned long long m = __ballot(pos);
    if ((t & 63) == 0) masks[t >> 6] = m;
    inv[t] = -1;
    if (t < 32) inv[256 + t] = -1;
    __syncthreads();
    int P = 0;
    #pragma unroll
    for (int w = 0; w < 4; ++w) P += __popcll(masks[w]);
    const int w = t >> 6;
    int below = __popcll(masks[w] & ((1ull << (t & 63)) - 1ull));
    #pragma unroll
    for (int wi = 0; wi < 4; ++wi) if (wi < w) below += __popcll(masks[wi]);
    const int P32 = (P + 31) & ~31;
    const int dest = pos ? below : (P32 + (t - below));
    inv[dest] = (short)t;
    __syncthreads();

    const int q = (b - 256) * 4 + (t >> 6);     // 0..575
    const int d0 = (t & 63) * 4;
    const bool topR = q < 288;
    const int hidx = topR ? q : q - 288;
    const short oh = inv[hidx];
    ushort4 u = {0, 0, 0, 0};
    float bias = 0.f;
    if (oh >= 0) {
      const float wa = fabsf(W2[oh]);
      const float sc = topR ? wa : -wa;
      const float4 v = *(const float4*)(W1 + oh * 512 + (topR ? 0 : 256) + d0);
      u.x = f2bf(v.x * sc); u.y = f2bf(v.y * sc);
      u.z = f2bf(v.z * sc); u.w = f2bf(v.w * sc);
      bias = topR ? b1[oh] * wa : 0.f;
    }
    ((ushort4*)(Wc + q * 256))[d0 >> 2] = u;
    if (d0 == 0) b1f[q] = bias;
    if (b == 256 && t == 0) *(int*)(ws + PV_OFF) = P;
    return;
  }
  {
    __shared__ float part[4][64];
    const int w = t >> 6, dl = t & 63;
    const int d = (b - 400) * 64 + dl;
    float acc = 0.f;
    const float* col = W1 + 256 + d;
    #pragma unroll 8
    for (int h = w * 64; h < w * 64 + 64; ++h) acc += W2[h] * col[h * 512];
    part[w][dl] = acc;
    __syncthreads();
    if (w == 0) {
      float s = part[0][dl] + part[1][dl] + part[2][dl] + part[3][dl];
      Wc[576 * 256 + d] = f2bf(s);
    }
    if (b == 400) {
      for (int r = 577; r < 592; ++r) Wc[r * 256 + t] = 0;
      if (t == 0) b1f[576] = b2[0];
      if (t < 15) b1f[577 + t] = 0.f;
    }
  }
}

// ---------------- k1: fc1 GEMM via bf16 MFMA -> pk-f16 outputs ----------------
// G[i][q] = zb[i].Wcat[q] + b1f[q]; R-half -> R2[hp][i] u32 pairs;
// C-half -> Ct[hpg][j][w4] u32 pairs; q-tile 36 -> Kv f32.
__global__ __launch_bounds__(64) void k1_mfma(char* __restrict__ ws) {
  __shared__ float tile[16][17];
  const unsigned short* zb = (const unsigned short*)(ws + ZB_OFF);
  const unsigned short* Wcu = (const unsigned short*)(ws + WC_OFF);
  const float* b1f = (const float*)(ws + B1F_OFF);
  unsigned int* R2 = (unsigned int*)(ws + R2_OFF);
  unsigned int* Ct = (unsigned int*)(ws + CT_OFF);
  float* Kv = (float*)(ws + KV_OFF);

  const int l = threadIdx.x;
  const int i0 = blockIdx.x * 16, q0 = blockIdx.y * 16;
  const short* A = (const short*)zb + (i0 + (l & 15)) * 256 + ((l >> 4) * 8);
  const short* B = (const short*)Wcu + (q0 + (l & 15)) * 256 + ((l >> 4) * 8);
  floatx4 acc = {0.f, 0.f, 0.f, 0.f};
  #pragma unroll
  for (int kk = 0; kk < 8; ++kk) {
    short8 a  = *(const short8*)(A + kk * 32);
    short8 bb = *(const short8*)(B + kk * 32);
    acc = __builtin_amdgcn_mfma_f32_16x16x32_bf16(a, bb, acc, 0, 0, 0);
  }
  const int col = l & 15, r0 = (l >> 4) * 4;   // D: col=lane&15, row=(lane>>4)*4+reg

  if (q0 < 576) {
    // write G-tile (rows = i or j, cols = q) into LDS for pair-packing
    const float bias = b1f[q0 + col];
    #pragma unroll
    for (int q = 0; q < 4; ++q) tile[r0 + q][col] = acc[q] + bias;
    __syncthreads();
    const int il = l & 15, g2 = l >> 4;        // g2 in 0..3
    if (q0 < 288) {
      #pragma unroll
      for (int e = 0; e < 2; ++e) {
        const int qc = g2 * 4 + e * 2;
        const unsigned int pk = pkf16(tile[il][qc], tile[il][qc + 1]);
        R2[((q0 >> 1) + g2 * 2 + e) * 1024 + (i0 + il)] = pk;
      }
    } else {
      unsigned int pk0 = pkf16(tile[il][g2 * 4 + 0], tile[il][g2 * 4 + 1]);
      unsigned int pk1 = pkf16(tile[il][g2 * 4 + 2], tile[il][g2 * 4 + 3]);
      const int hpg = ((q0 - 288) >> 3) + (g2 >> 1);
      unsigned int* dst = Ct + (hpg * 1024 + (i0 + il)) * 4 + (g2 & 1) * 2;
      dst[0] = pk0; dst[1] = pk1;
    }
  } else if (col == 0) {
    const float bias = b1f[576];               // = b2
    #pragma unroll
    for (int q = 0; q < 4; ++q) Kv[i0 + r0 + q] = acc[q] + bias;
  }
}

// ---------------- k2: pairwise decode, pk-f16, LDS-R + reg-C ----------------
// Block 256 thr (4 waves), tile 16i x 64j. Lane = (li 0..3) x (lj 0..15);
// per-lane outputs 4i x 4j. Wave w: sign-pure chunks {w, w+4, w+8(w0)}.
// R staged once to LDS (9 KB); C loaded coalesced dwordx4 per hpg, 2-deep pipe.
__global__ __launch_bounds__(256) void k2_pair(const unsigned int* __restrict__ R2,
    const unsigned int* __restrict__ Ct, const float* __restrict__ Kv,
    const int* __restrict__ Pp, float* __restrict__ out) {
  __shared__ unsigned int Rl[144][16];     // 9 KiB
  __shared__ float part[4][16][64];        // 16 KiB
  const int t = threadIdx.x;
  const int lane = t & 63, w = t >> 6;
  const int li = lane >> 4, lj = lane & 15;
  const int i0 = blockIdx.x * 16, j0 = blockIdx.y * 64;

  // stage R: 2304 u32, 9 per thread, coalesced in 16-lane groups
  #pragma unroll
  for (int k = 0; k < 9; ++k) {
    const int n = k * 256 + t;
    ((unsigned int*)Rl)[n] = R2[(n >> 4) * 1024 + i0 + (n & 15)];
  }
  __syncthreads();

  const int P = Pp[0];
  float acc[4][4] = {};

  // C load: buf[jj] = Ct[hpg][j0 + lj + 16*jj][0..3]
#define LOADC(BUF, HPG) do { \
    _Pragma("unroll") \
    for (int jj = 0; jj < 4; ++jj) \
      BUF[jj] = *(const uint4v*)(Ct + (((HPG) * 1024) + j0 + lj + 16 * jj) * 4); \
  } while (0)

  // compute one hpg (4 h-pairs): 4 ds_read_b128 + 128 pk-VALU
#define COMPG(BUF, HPG) do { \
    _Pragma("unroll") \
    for (int hp2 = 0; hp2 < 4; ++hp2) { \
      const uint4v ra = *(const uint4v*)&Rl[(HPG) * 4 + hp2][li * 4]; \
      _Pragma("unroll") \
      for (int ii = 0; ii < 4; ++ii) \
        _Pragma("unroll") \
        for (int jj = 0; jj < 4; ++jj) \
          pkmaxdot(ra[ii], BUF[jj][hp2], mul, acc[ii][jj]); \
    } \
  } while (0)

#define DO_CHUNK(CH) do { \
    const int ch_ = (CH); \
    const unsigned int mul = (ch_ * 32 < P) ? 0x3C003C00u : 0xBC00BC00u; \
    const int hb = ch_ * 4; \
    uint4v c0[4], c1[4]; \
    LOADC(c0, hb); LOADC(c1, hb + 1); \
    COMPG(c0, hb + 0); LOADC(c0, hb + 2); \
    COMPG(c1, hb + 1); LOADC(c1, hb + 3); \
    COMPG(c0, hb + 2); \
    COMPG(c1, hb + 3); \
  } while (0)

  DO_CHUNK(w);
  DO_CHUNK(w + 4);
  if (w == 0) DO_CHUNK(8);

#undef LOADC
#undef COMPG
#undef DO_CHUNK

  #pragma unroll
  for (int ii = 0; ii < 4; ++ii)
    #pragma unroll
    for (int jj = 0; jj < 4; ++jj)
      part[w][li * 4 + ii][lj + 16 * jj] = acc[ii][jj];
  __syncthreads();

  // combine + sigmoid: 256 threads x 4 outputs
  const int jl = t & 63, ib = (t >> 6) * 4;
  const float kv = Kv[j0 + jl];
  #pragma unroll
  for (int u = 0; u < 4; ++u) {
    const int il = ib + u;
    const float x = part[0][il][jl] + part[1][il][jl] +
                    part[2][il][jl] + part[3][il][jl] + kv;
    out[(i0 + il) * NN + j0 + jl] = 1.f / (1.f + __expf(-x));
  }
}

extern "C" void kernel_launch(void* const* d_in, const int* in_sizes, int n_in,
                              void* d_out, int out_size, void* d_ws, size_t ws_size,
                              hipStream_t stream) {
  const float* z  = (const float*)d_in[0];
  const float* W1 = (const float*)d_in[1];
  const float* b1 = (const float*)d_in[2];
  const float* W2 = (const float*)d_in[3];
  const float* b2 = (const float*)d_in[4];
  float* out = (float*)d_out;
  char* ws = (char*)d_ws;

  k0_prep<<<404, 256, 0, stream>>>(z, W1, b1, W2, b2, ws);
  k1_mfma<<<dim3(64, 37), 64, 0, stream>>>(ws);
  k2_pair<<<dim3(64, 16), 256, 0, stream>>>(
      (const unsigned int*)(ws + R2_OFF), (const unsigned int*)(ws + CT_OFF),
      (const float*)(ws + KV_OFF), (const int*)(ws + PV_OFF), out);
}